// Round 6
// baseline (58.078 us; speedup 1.0000x reference)
//
#include <hip/hip_runtime.h>
#include <math.h>

// Problem shape (fixed by setup_inputs): B=4, N=M=4096, D=3, fp32.
#define BATCH  4
#define NPTS   4096
#define TPB    256
#define SLICES 8                    // M-slices per row (threads per row)
#define ROWS_PB (TPB / SLICES)      // 32 rows per block
#define RCHUNKS (NPTS / ROWS_PB)    // 128 row-chunks -> grid 128*4*2 = 1024 blocks
#define SEG    1024                 // Y points staged per stint (16 KB as float4)
#define NSEG   (NPTS / SEG)         // 4 stints cover all of M in-block
#define JPT    (SEG / SLICES)       // 128 j's per thread per stint
#define FP_SCALE 268435456.0        // 2^28 fixed-point scale (deterministic sum)

// ws layout: [0..8) u64 fixed-point total | [8..12) u32 arrival counter.

__global__ void ahd_init(unsigned long long* __restrict__ total,
                         unsigned int* __restrict__ counter) {
    *total = 0ULL;
    *counter = 0u;
}

// One fused kernel: each block = 32 rows x full M.
// Thread t: row = rc*32 + (t>>3), slice s = t&7 handles j = jj*8+s (interleaved
// so a wave's 8 distinct float4 LDS reads span all 32 banks conflict-free,
// with 8-way same-address broadcast).
__global__ __launch_bounds__(TPB) void ahd_fused(
    const float* __restrict__ set1, const float* __restrict__ set2,
    unsigned long long* __restrict__ total, unsigned int* __restrict__ counter,
    float* __restrict__ out)
{
    const int dir = blockIdx.z, b = blockIdx.y, rc = blockIdx.x;
    const float* __restrict__ X = dir ? set2 : set1;
    const float* __restrict__ Y = dir ? set1 : set2;

    __shared__ float4 ls[SEG];                  // {y0,y1,y2,|y|^2}
    __shared__ unsigned long long ws[TPB / 64];

    const int tid = threadIdx.x;
    const int s   = tid & (SLICES - 1);
    const int row = rc * ROWS_PB + (tid >> 3);

    // Row data (8 threads share a row -> L1 broadcast).
    const float* xp = X + ((size_t)b * NPTS + row) * 3;
    const float x0 = xp[0], x1 = xp[1], x2 = xp[2];
    const float nx0 = -2.0f * x0, nx1 = -2.0f * x1, nx2 = -2.0f * x2;
    const float hx  = fmaf(x0, x0, fmaf(x1, x1, x2 * x2));

    float acc = 3.4e38f;   // running min of (|y|^2 - 2 x.y) over this slice

    for (int seg = 0; seg < NSEG; ++seg) {
        if (seg) __syncthreads();   // all reads of previous stint done
        // Stage SEG points: thread t unpacks points 4t..4t+3 from 3 float4
        // vector loads (AoS xyz stream is 16B-aligned at these offsets).
        const float4* f4 = (const float4*)(Y + ((size_t)b * NPTS + seg * SEG) * 3);
        const float4 f0 = f4[tid * 3 + 0];
        const float4 f1 = f4[tid * 3 + 1];
        const float4 f2 = f4[tid * 3 + 2];
        ls[4 * tid + 0] = make_float4(f0.x, f0.y, f0.z,
                           fmaf(f0.x, f0.x, fmaf(f0.y, f0.y, f0.z * f0.z)));
        ls[4 * tid + 1] = make_float4(f0.w, f1.x, f1.y,
                           fmaf(f0.w, f0.w, fmaf(f1.x, f1.x, f1.y * f1.y)));
        ls[4 * tid + 2] = make_float4(f1.z, f1.w, f2.x,
                           fmaf(f1.z, f1.z, fmaf(f1.w, f1.w, f2.x * f2.x)));
        ls[4 * tid + 3] = make_float4(f2.y, f2.z, f2.w,
                           fmaf(f2.y, f2.y, fmaf(f2.z, f2.z, f2.w * f2.w)));
        __syncthreads();

        // Paired j-loop: fminf(acc, fminf(qa,qb)) -> v_min3_f32, 3.5 ops/pair.
        #pragma unroll 4
        for (int jj = 0; jj < JPT; jj += 2) {
            const float4 ya = ls[jj * SLICES + s];
            const float4 yb = ls[(jj + 1) * SLICES + s];
            const float qa = fmaf(nx0, ya.x, fmaf(nx1, ya.y, fmaf(nx2, ya.z, ya.w)));
            const float qb = fmaf(nx0, yb.x, fmaf(nx1, yb.y, fmaf(nx2, yb.z, yb.w)));
            acc = fminf(acc, fminf(qa, qb));
        }
    }

    // Combine the 8 slice-mins of each row (lanes differing in low 3 bits).
    acc = fminf(acc, __shfl_xor(acc, 1, 64));
    acc = fminf(acc, __shfl_xor(acc, 2, 64));
    acc = fminf(acc, __shfl_xor(acc, 4, 64));

    float d = sqrtf(fmaxf(acc + hx, 0.0f));
    if (s != 0) d = 0.0f;           // count each row exactly once

    // Wave sum (8 nonzero lanes, deterministic tree).
    d += __shfl_xor(d, 8, 64);
    d += __shfl_xor(d, 16, 64);
    d += __shfl_xor(d, 32, 64);

    const int lane = tid & 63, w = tid >> 6;
    if (lane == 0)
        ws[w] = (unsigned long long)((double)d * FP_SCALE);
    __syncthreads();

    if (tid == 0) {
        const unsigned long long bs = ws[0] + ws[1] + ws[2] + ws[3];
        atomicAdd(total, bs);
        __threadfence();
        const unsigned int cnt = atomicAdd(counter, 1u);
        if (cnt == (unsigned int)(RCHUNKS * BATCH * 2 - 1)) {
            // last arriver: all adds visible (fence + counter order)
            const unsigned long long fin = atomicAdd(total, 0ULL);
            out[0] = (float)((double)fin * (1.0 / FP_SCALE)
                             * (1.0 / (double)(BATCH * NPTS)));
        }
    }
}

extern "C" void kernel_launch(void* const* d_in, const int* in_sizes, int n_in,
                              void* d_out, int out_size, void* d_ws, size_t ws_size,
                              hipStream_t stream) {
    const float* set1 = (const float*)d_in[0];
    const float* set2 = (const float*)d_in[1];
    float* out = (float*)d_out;

    unsigned long long* total = (unsigned long long*)d_ws;
    unsigned int* counter = (unsigned int*)((char*)d_ws + 8);

    ahd_init<<<1, 1, 0, stream>>>(total, counter);
    dim3 grid(RCHUNKS, BATCH, 2);
    ahd_fused<<<grid, dim3(TPB), 0, stream>>>(set1, set2, total, counter, out);
}

// Round 7
// 29.083 us; speedup vs baseline: 1.9969x; 1.9969x over previous
//
#include <hip/hip_runtime.h>
#include <math.h>

// Problem shape (fixed by setup_inputs): B=4, N=M=4096, D=3, fp32.
#define BATCH 4
#define NPTS  4096
#define RPB   256                 // threads per block
#define ROWS  8                   // rows (X points) per thread -> 2 LDS B/pair
#define ROWS_PER_BLOCK (RPB * ROWS)          // 2048
#define CHUNKS (NPTS / ROWS_PER_BLOCK)       // 2 row-chunks
#define SEGS  32                  // m-split -> 2*32*4*2 = 512 blocks = 2/CU
#define SEG_LEN (NPTS / SEGS)     // 128 Y points staged per block

#define RED_BLOCKS 128            // kernel-2 grid (128*256 = 32768 = one thread/row)
#define FP_SCALE   268435456.0    // 2^28 fixed-point scale for deterministic sum

// ws layout: [0..8) u64 fixed-point total | [8..12) u32 arrival counter |
//            [64 ..) float part[2][BATCH][SEGS][NPTS]  (4 MB)

// Gram-form partial min over one Y segment; non-atomic store (each slot
// written exactly once -> no init pass, no atomics, no memset dispatch).
// ROWS=8 register blocking: one broadcast ds_read_b128 feeds 8 rows
// (2 LDS bytes/pair, under the min3 VALU floor); 8 independent min chains
// give enough ILP to hide latency at 2 blocks/CU.
__global__ __launch_bounds__(RPB) void ahd_min_kernel(
    const float* __restrict__ set1, const float* __restrict__ set2,
    float* __restrict__ part, unsigned long long* __restrict__ total,
    unsigned int* __restrict__ counter)
{
    // One designated thread re-inits kernel-2's accumulators every call
    // (kernel boundary orders this before any kernel-2 read).
    if (blockIdx.x == 0 && blockIdx.y == 0 && blockIdx.z == 0 && threadIdx.x == 0) {
        *total = 0ULL;
        *counter = 0u;
    }

    const int dir      = blockIdx.z;
    const int b        = blockIdx.y;
    const int rowChunk = blockIdx.x / SEGS;
    const int seg      = blockIdx.x % SEGS;

    const float* __restrict__ X = dir ? set2 : set1;
    const float* __restrict__ Y = dir ? set1 : set2;

    __shared__ float4 ys[SEG_LEN];   // {y0, y1, y2, |y|^2}

    const float* ybase = Y + ((size_t)b * NPTS + (size_t)seg * SEG_LEN) * 3;
    if (threadIdx.x < SEG_LEN) {
        const int i = threadIdx.x;
        const float y0 = ybase[i * 3 + 0];
        const float y1 = ybase[i * 3 + 1];
        const float y2 = ybase[i * 3 + 2];
        ys[i] = make_float4(y0, y1, y2, fmaf(y0, y0, fmaf(y1, y1, y2 * y2)));
    }
    __syncthreads();

    float nx0[ROWS], nx1[ROWS], nx2[ROWS], hx[ROWS], acc[ROWS];
    const int rowBase = rowChunk * ROWS_PER_BLOCK + threadIdx.x;
    #pragma unroll
    for (int r = 0; r < ROWS; ++r) {
        const float* xp = X + ((size_t)b * NPTS + rowBase + r * RPB) * 3;
        const float x0 = xp[0], x1 = xp[1], x2 = xp[2];
        nx0[r] = -2.0f * x0;
        nx1[r] = -2.0f * x1;
        nx2[r] = -2.0f * x2;
        hx[r]  = fmaf(x0, x0, fmaf(x1, x1, x2 * x2));
        acc[r] = 3.4e38f;
    }

    // Paired j-loop: fminf(acc, fminf(qa,qb)) -> v_min3_f32 (3.5 ops/pair).
    // unroll 2 => 4 broadcast ds_read_b128 in flight per lgkmcnt wait,
    // 56 VALU ops between waits.
    #pragma unroll 2
    for (int j = 0; j < SEG_LEN; j += 2) {
        const float4 ya = ys[j];       // broadcast reads, conflict-free
        const float4 yb = ys[j + 1];
        #pragma unroll
        for (int r = 0; r < ROWS; ++r) {
            const float qa = fmaf(nx0[r], ya.x,
                             fmaf(nx1[r], ya.y,
                             fmaf(nx2[r], ya.z, ya.w)));
            const float qb = fmaf(nx0[r], yb.x,
                             fmaf(nx1[r], yb.y,
                             fmaf(nx2[r], yb.z, yb.w)));
            acc[r] = fminf(acc[r], fminf(qa, qb));
        }
    }

    // partial d^2 for this segment, clamped >= 0; coalesced plain stores
    float* dst = part + (((size_t)(dir * BATCH + b) * SEGS + seg) * NPTS);
    #pragma unroll
    for (int r = 0; r < ROWS; ++r)
        dst[rowBase + r * RPB] = fmaxf(acc[r] + hx[r], 0.0f);
}

// Kernel 2: per row min over SEGS partials, sqrt, deterministic fixed-point
// sum via one u64 atomic; last-arriving block finalizes out[0].
__global__ __launch_bounds__(RPB) void ahd_reduce_kernel(
    const float* __restrict__ part, unsigned long long* __restrict__ total,
    unsigned int* __restrict__ counter, float* __restrict__ out)
{
    const int g    = blockIdx.x * RPB + threadIdx.x;   // 0..32767
    const int dirb = g >> 12;                          // which [dir][b] plane
    const int n    = g & (NPTS - 1);

    const float* p = part + ((size_t)dirb * SEGS) * NPTS + n;
    float m = p[0];
    #pragma unroll 8
    for (int s = 1; s < SEGS; ++s)
        m = fminf(m, p[(size_t)s * NPTS]);             // coalesced per seg

    float d = sqrtf(m);

    // wave tree-sum (deterministic order)
    #pragma unroll
    for (int off = 32; off > 0; off >>= 1)
        d += __shfl_down(d, off, 64);

    __shared__ unsigned long long ws[4];
    const int lane = threadIdx.x & 63;
    const int w    = threadIdx.x >> 6;
    if (lane == 0)
        ws[w] = (unsigned long long)((double)d * FP_SCALE);
    __syncthreads();

    if (threadIdx.x == 0) {
        const unsigned long long bs = ws[0] + ws[1] + ws[2] + ws[3];
        atomicAdd(total, bs);
        __threadfence();
        const unsigned int cnt = atomicAdd(counter, 1u);
        if (cnt == (unsigned int)(gridDim.x - 1)) {
            // last arriver: all total-adds are visible (fence + counter order)
            const unsigned long long fin = atomicAdd(total, 0ULL);
            out[0] = (float)((double)fin * (1.0 / FP_SCALE)
                             * (1.0 / (double)(BATCH * NPTS)));
        }
    }
}

extern "C" void kernel_launch(void* const* d_in, const int* in_sizes, int n_in,
                              void* d_out, int out_size, void* d_ws, size_t ws_size,
                              hipStream_t stream) {
    const float* set1 = (const float*)d_in[0];
    const float* set2 = (const float*)d_in[1];
    float* out = (float*)d_out;

    unsigned long long* total = (unsigned long long*)d_ws;
    unsigned int* counter = (unsigned int*)((char*)d_ws + 8);
    float* part = (float*)((char*)d_ws + 64);   // 2*BATCH*SEGS*NPTS floats = 4 MB

    dim3 grid(CHUNKS * SEGS, BATCH, 2);
    ahd_min_kernel<<<grid, dim3(RPB), 0, stream>>>(set1, set2, part, total, counter);
    ahd_reduce_kernel<<<RED_BLOCKS, dim3(RPB), 0, stream>>>(part, total, counter, out);
}